// Round 4
// baseline (2117.828 us; speedup 1.0000x reference)
//
#include <hip/hip_runtime.h>

#define LEAKY_SLOPE 0.01f
#define BSH 6
#define BSZ 64            // nodes per bucket

__device__ __forceinline__ unsigned short f2bf(float f) {
    unsigned int u = __builtin_bit_cast(unsigned int, f);
    u = (u + 0x7FFFu + ((u >> 16) & 1u)) >> 16;   // round-to-nearest-even
    return (unsigned short)u;
}
__device__ __forceinline__ float bf2f(unsigned short h) {
    return __builtin_bit_cast(float, ((unsigned int)h) << 16);
}

// ---------------------------------------------------------------------------
// deg histogram by dst
// ---------------------------------------------------------------------------
__global__ void count_kernel(const int* __restrict__ dst, int* __restrict__ deg, int E) {
    int i = blockIdx.x * blockDim.x + threadIdx.x;
    if (i < E) atomicAdd(&deg[dst[i]], 1);
}

// ---------------------------------------------------------------------------
// dis = rsqrt(deg+1); bucket counts = wave-reduced deg (bucket == 64 nodes,
// wave-aligned: no atomics needed)
// ---------------------------------------------------------------------------
__global__ __launch_bounds__(256) void prep_kernel(const int* __restrict__ deg,
                                                   float* __restrict__ dis,
                                                   int* __restrict__ bcnt, int n, int nb) {
    int i = blockIdx.x * 256 + threadIdx.x;
    int d = (i < n) ? deg[i] : 0;
    if (i < n) dis[i] = rsqrtf((float)d + 1.0f);
    int v = d;
    for (int off = 1; off < 64; off <<= 1) v += __shfl_xor(v, off, 64);
    int b = i >> BSH;
    if ((threadIdx.x & 63) == 0 && b < nb) bcnt[b] = v;
}

// ---------------------------------------------------------------------------
// single-block scan of bucket counts -> exclusive offsets + cursor init
// ---------------------------------------------------------------------------
__global__ __launch_bounds__(256) void scan_kernel(const int* __restrict__ bcnt,
                                                   int* __restrict__ boff,
                                                   int* __restrict__ cur16, int nb) {
    __shared__ int s[256];
    __shared__ int carry;
    int t = threadIdx.x;
    if (t == 0) carry = 0;
    __syncthreads();
    for (int base = 0; base < nb; base += 256) {
        int v = (base + t < nb) ? bcnt[base + t] : 0;
        s[t] = v;
        __syncthreads();
        for (int off = 1; off < 256; off <<= 1) {
            int u = (t >= off) ? s[t - off] : 0;
            __syncthreads();
            s[t] += u;
            __syncthreads();
        }
        int excl = carry + s[t] - v;
        if (base + t < nb) {
            boff[base + t] = excl;
            cur16[(size_t)(base + t) * 16] = excl;   // 64B-padded cursor = offset
        }
        __syncthreads();
        if (t == 0) carry += s[255];
        __syncthreads();
    }
    if (t == 0) boff[nb] = carry;
}

// ---------------------------------------------------------------------------
// scatter edges to bucket regions, packed (src | dst_low<<17); writes within a
// bucket are sequential -> L2-hot lines, ~6.4MB writeback instead of ~100MB
// ---------------------------------------------------------------------------
__global__ void scatter_kernel(const int* __restrict__ src, const int* __restrict__ dst,
                               int* __restrict__ cur16, unsigned* __restrict__ pairs, int E) {
    int e = blockIdx.x * blockDim.x + threadIdx.x;
    if (e < E) {
        int d = dst[e];
        int b = d >> BSH;
        int pos = atomicAdd(&cur16[(size_t)b * 16], 1);
        __builtin_nontemporal_store((unsigned)src[e] | ((unsigned)(d & (BSZ - 1)) << 17),
                                    &pairs[pos]);
    }
}

// ---------------------------------------------------------------------------
// gemm1: Hs1 = (X[N,128] @ W1[128,64]) * dis -> bf16
// ---------------------------------------------------------------------------
__global__ __launch_bounds__(256) void gemm1_kernel(const float* __restrict__ X,
                                                    const float* __restrict__ W,
                                                    const float* __restrict__ dis,
                                                    unsigned short* __restrict__ Hh, int N) {
    __shared__ float Xs[16 * 128];
    int tid = threadIdx.x;
    int row0 = blockIdx.x * 16;
    for (int i = tid * 4; i < 16 * 128; i += 256 * 4)
        *(float4*)&Xs[i] = *(const float4*)&X[(size_t)row0 * 128 + i];
    __syncthreads();

    int c = tid & 63;
    int g = tid >> 6;
    float acc[4] = {0.f, 0.f, 0.f, 0.f};
    for (int kk = 0; kk < 128; kk += 16) {
        float w[16];
#pragma unroll
        for (int k = 0; k < 16; ++k) w[k] = W[(kk + k) * 64 + c];
#pragma unroll
        for (int r = 0; r < 4; ++r) {
            int row = g + r * 4;
#pragma unroll
            for (int k4 = 0; k4 < 16; k4 += 4) {
                float4 x4 = *(float4*)&Xs[row * 128 + kk + k4];
                acc[r] += x4.x * w[k4] + x4.y * w[k4 + 1] + x4.z * w[k4 + 2] + x4.w * w[k4 + 3];
            }
        }
    }
#pragma unroll
    for (int r = 0; r < 4; ++r) {
        int row = row0 + g + r * 4;
        Hh[(size_t)row * 64 + c] = f2bf(acc[r] * dis[row]);
    }
}

// ---------------------------------------------------------------------------
// Bucketed edge-parallel aggregation. One block per bucket (64 nodes).
// LDS accum rows init to self term; waves process edges in batches of 64
// (coalesced packed loads, readlane broadcast, 16 gathers in flight),
// atomicAdd (ds_add_f32) into LDS. Epilogue per MODE:
//   0: h1 = leaky(acc*d + b1); out = bf16((h1@W2)*d)
//   1: h2 = leaky(acc*d + b2); out = bf16(h2*d)
//   2: g = acc*d; mu = g@Wmu+bmu, ls = g@Wls+bls (lane halves)
// ---------------------------------------------------------------------------
template <int MODE>
__global__ __launch_bounds__(256) void agg_kernel(
    const unsigned short* __restrict__ Hh, const unsigned* __restrict__ pairs,
    const int* __restrict__ boff, const float* __restrict__ dis,
    const float* __restrict__ bias, const float* __restrict__ Wa,
    const float* __restrict__ Wb, const float* __restrict__ bmu,
    const float* __restrict__ bls, unsigned short* __restrict__ Oh,
    float* __restrict__ mu, float* __restrict__ ls, int n) {
    __shared__ float accum[BSZ * 64];
    int b = blockIdx.x;
    int lane = threadIdx.x & 63;
    int w = threadIdx.x >> 6;
    int node0 = b << BSH;

    float wc[64];
    if (MODE == 0) {
#pragma unroll
        for (int k = 0; k < 64; ++k) wc[k] = Wa[k * 64 + lane];
    } else if (MODE == 2) {
        const float* Wp = (lane >= 32) ? Wb : Wa;
        int cc = lane & 31;
#pragma unroll
        for (int k = 0; k < 64; ++k) wc[k] = Wp[k * 32 + cc];
    }
    float bv = (MODE < 2) ? bias[lane] : ((lane >= 32) ? bls[lane & 31] : bmu[lane & 31]);

    for (int r = w; r < BSZ; r += 4) {
        int node = node0 + r;
        accum[r * 64 + lane] = (node < n) ? bf2f(Hh[(size_t)node * 64 + lane]) : 0.f;
    }
    __syncthreads();

    int e0 = boff[b];
    int cnt = boff[b + 1] - e0;
    for (int base = w * 64; base < cnt; base += 256) {
        int m = min(64, cnt - base);
        unsigned pk = 0;
        if (base + lane < cnt) pk = pairs[e0 + base + lane];
        for (int kk = 0; kk < m; kk += 16) {
            int lim = min(16, m - kk);
            float h[16];
            int dl[16];
#pragma unroll
            for (int j = 0; j < 16; ++j)
                if (j < lim) {
                    unsigned p = (unsigned)__builtin_amdgcn_readlane((int)pk, kk + j);
                    dl[j] = (int)(p >> 17);
                    h[j] = bf2f(Hh[(size_t)(p & 0x1FFFFu) * 64 + lane]);
                }
#pragma unroll
            for (int j = 0; j < 16; ++j)
                if (j < lim) atomicAdd(&accum[dl[j] * 64 + lane], h[j]);
        }
    }
    __syncthreads();

    for (int r = w; r < BSZ; r += 4) {
        int node = node0 + r;
        if (node >= n) continue;
        float accv = accum[r * 64 + lane];
        float d = dis[node];
        if (MODE == 0) {
            float h1 = fmaf(accv, d, bv);
            h1 = h1 > 0.f ? h1 : LEAKY_SLOPE * h1;
            int hb = __builtin_bit_cast(int, h1);
            float o = 0.f;
#pragma unroll
            for (int k = 0; k < 64; ++k) {
                float hk = __builtin_bit_cast(float, __builtin_amdgcn_readlane(hb, k));
                o = fmaf(hk, wc[k], o);
            }
            Oh[(size_t)node * 64 + lane] = f2bf(o * d);
        } else if (MODE == 1) {
            float h2 = fmaf(accv, d, bv);
            h2 = h2 > 0.f ? h2 : LEAKY_SLOPE * h2;
            Oh[(size_t)node * 64 + lane] = f2bf(h2 * d);
        } else {
            float g = accv * d;
            int gb = __builtin_bit_cast(int, g);
            float o = bv;
#pragma unroll
            for (int k = 0; k < 64; ++k) {
                float gk = __builtin_bit_cast(float, __builtin_amdgcn_readlane(gb, k));
                o = fmaf(gk, wc[k], o);
            }
            float* outp = (lane >= 32) ? ls : mu;
            outp[(size_t)node * 32 + (lane & 31)] = o;
        }
    }
}

// ---------------------------------------------------------------------------
extern "C" void kernel_launch(void* const* d_in, const int* in_sizes, int n_in,
                              void* d_out, int out_size, void* d_ws, size_t ws_size,
                              hipStream_t stream) {
    const float* x   = (const float*)d_in[0];
    const int*   ei  = (const int*)d_in[1];
    const float* W1  = (const float*)d_in[2];
    const float* b1  = (const float*)d_in[3];
    const float* W2  = (const float*)d_in[4];
    const float* b2  = (const float*)d_in[5];
    const float* Wmu = (const float*)d_in[6];
    const float* bmu = (const float*)d_in[7];
    const float* Wls = (const float*)d_in[8];
    const float* bls = (const float*)d_in[9];

    const int N = in_sizes[0] / 128;   // 100000
    const int E = in_sizes[1] / 2;     // 1600000
    const int NB = (N + BSZ - 1) / BSZ;  // 1563 buckets
    const int* src  = ei;
    const int* dstp = ei + E;

    auto align64 = [](size_t v) { return (v + 63) & ~(size_t)63; };
    char* ws = (char*)d_ws;
    int*   deg   = (int*)ws;   ws += align64((size_t)N * 4);
    float* dis   = (float*)ws; ws += align64((size_t)N * 4);
    int*   bcnt  = (int*)ws;   ws += align64((size_t)NB * 4);
    int*   boff  = (int*)ws;   ws += align64((size_t)(NB + 1) * 4);
    int*   cur16 = (int*)ws;   ws += align64((size_t)NB * 16 * 4);
    unsigned* pairs = (unsigned*)ws; ws += align64((size_t)E * 4);
    unsigned short* bufH0 = (unsigned short*)ws; ws += align64((size_t)N * 64 * 2);
    unsigned short* bufH1 = (unsigned short*)ws; ws += align64((size_t)N * 64 * 2);

    float* mu = (float*)d_out;
    float* ls = mu + (size_t)N * 32;

    const int eblocks = (E + 255) / 256;
    const int nblocks = (N + 255) / 256;

    hipMemsetAsync(deg, 0, (size_t)N * sizeof(int), stream);
    count_kernel<<<eblocks, 256, 0, stream>>>(dstp, deg, E);
    prep_kernel<<<nblocks, 256, 0, stream>>>(deg, dis, bcnt, N, NB);
    scan_kernel<<<1, 256, 0, stream>>>(bcnt, boff, cur16, NB);
    scatter_kernel<<<eblocks, 256, 0, stream>>>(src, dstp, cur16, pairs, E);
    gemm1_kernel<<<N / 16, 256, 0, stream>>>(x, W1, dis, bufH0, N);

    agg_kernel<0><<<NB, 256, 0, stream>>>(bufH0, pairs, boff, dis, b1, W2,
                                          nullptr, nullptr, nullptr, bufH1,
                                          nullptr, nullptr, N);
    agg_kernel<1><<<NB, 256, 0, stream>>>(bufH1, pairs, boff, dis, b2, nullptr,
                                          nullptr, nullptr, nullptr, bufH0,
                                          nullptr, nullptr, N);
    agg_kernel<2><<<NB, 256, 0, stream>>>(bufH0, pairs, boff, dis, nullptr, Wmu,
                                          Wls, bmu, bls, nullptr, mu, ls, N);
}

// Round 5
// 504.354 us; speedup vs baseline: 4.1991x; 4.1991x over previous
//
#include <hip/hip_runtime.h>

#define LEAKY_SLOPE 0.01f

__device__ __forceinline__ unsigned short f2bf(float f) {
    unsigned int u = __builtin_bit_cast(unsigned int, f);
    u = (u + 0x7FFFu + ((u >> 16) & 1u)) >> 16;   // round-to-nearest-even
    return (unsigned short)u;
}
__device__ __forceinline__ float bf2f(unsigned short h) {
    return __builtin_bit_cast(float, ((unsigned int)h) << 16);
}

// ---------------------------------------------------------------------------
// CSR build: histogram by dst
// ---------------------------------------------------------------------------
__global__ void count_kernel(const int* __restrict__ dst, int* __restrict__ deg, int E) {
    int i = blockIdx.x * blockDim.x + threadIdx.x;
    if (i < E) atomicAdd(&deg[dst[i]], 1);
}

__global__ void scan_block_sums(const int* __restrict__ deg, int* __restrict__ bsum, int n) {
    __shared__ int sdata[256];
    int i = blockIdx.x * 256 + threadIdx.x;
    int t = threadIdx.x;
    sdata[t] = (i < n) ? deg[i] : 0;
    __syncthreads();
    for (int s = 128; s > 0; s >>= 1) {
        if (t < s) sdata[t] += sdata[t + s];
        __syncthreads();
    }
    if (t == 0) bsum[blockIdx.x] = sdata[0];
}

__global__ void scan_partials(int* __restrict__ bsum, int nb, int* __restrict__ rp_end, int E) {
    __shared__ int s[512];
    int t = threadIdx.x;
    int orig = (t < nb) ? bsum[t] : 0;
    s[t] = orig;
    __syncthreads();
    for (int off = 1; off < 512; off <<= 1) {
        int v = (t >= off) ? s[t - off] : 0;
        __syncthreads();
        s[t] += v;
        __syncthreads();
    }
    if (t < nb) bsum[t] = s[t] - orig;   // exclusive
    if (t == 0) rp_end[0] = E;           // row_ptr[N] = E
}

__global__ void scan_final(const int* __restrict__ deg, const int* __restrict__ bsum,
                           int* __restrict__ rp, int* __restrict__ next,
                           float* __restrict__ dis, int n) {
    __shared__ int s[256];
    int i = blockIdx.x * 256 + threadIdx.x;
    int t = threadIdx.x;
    int orig = (i < n) ? deg[i] : 0;
    s[t] = orig;
    __syncthreads();
    for (int off = 1; off < 256; off <<= 1) {
        int v = (t >= off) ? s[t - off] : 0;
        __syncthreads();
        s[t] += v;
        __syncthreads();
    }
    if (i < n) {
        int excl = s[t] - orig + bsum[blockIdx.x];
        rp[i] = excl;
        next[i] = excl;
        dis[i] = rsqrtf((float)orig + 1.0f);   // +1 self-loop
    }
}

__global__ void fill_kernel(const int* __restrict__ src, const int* __restrict__ dst,
                            int* __restrict__ next, int* __restrict__ ssrc, int E) {
    int e = blockIdx.x * blockDim.x + threadIdx.x;
    if (e < E) {
        int d = dst[e];
        int pos = atomicAdd(&next[d], 1);
        __builtin_nontemporal_store(src[e], &ssrc[pos]);
    }
}

// ---------------------------------------------------------------------------
// gemm1: Hs1 = (X[N,128] @ W1[128,64]) * dis -> bf16
// ---------------------------------------------------------------------------
__global__ __launch_bounds__(256) void gemm1_kernel(const float* __restrict__ X,
                                                    const float* __restrict__ W,
                                                    const float* __restrict__ dis,
                                                    unsigned short* __restrict__ Hh, int N) {
    __shared__ float Xs[16 * 128];
    int tid = threadIdx.x;
    int row0 = blockIdx.x * 16;
    for (int i = tid * 4; i < 16 * 128; i += 256 * 4)
        *(float4*)&Xs[i] = *(const float4*)&X[(size_t)row0 * 128 + i];
    __syncthreads();

    int c = tid & 63;
    int g = tid >> 6;
    float acc[4] = {0.f, 0.f, 0.f, 0.f};
    for (int kk = 0; kk < 128; kk += 16) {
        float w[16];
#pragma unroll
        for (int k = 0; k < 16; ++k) w[k] = W[(kk + k) * 64 + c];
#pragma unroll
        for (int r = 0; r < 4; ++r) {
            int row = g + r * 4;
#pragma unroll
            for (int k4 = 0; k4 < 16; k4 += 4) {
                float4 x4 = *(float4*)&Xs[row * 128 + kk + k4];
                acc[r] += x4.x * w[k4] + x4.y * w[k4 + 1] + x4.z * w[k4 + 2] + x4.w * w[k4 + 3];
            }
        }
    }
#pragma unroll
    for (int r = 0; r < 4; ++r) {
        int row = row0 + g + r * 4;
        Hh[(size_t)row * 64 + c] = f2bf(acc[r] * dis[row]);
    }
}

// ---------------------------------------------------------------------------
// 8-deep pull gather: acc = self + sum of bf16 neighbor rows (fp32 accum).
// Straight-line named registers — no arrays, no predication inside the body.
// ---------------------------------------------------------------------------
#define GATHER_BODY(Hh, wid, lane)                                            \
    float acc = bf2f(Hh[(size_t)(wid) * 64 + (lane)]);                        \
    {                                                                         \
        int e0 = rp[wid], e1 = rp[(wid) + 1];                                 \
        const int* sp = ssrc + e0;                                            \
        int cnt = e1 - e0;                                                    \
        int i = 0;                                                            \
        float a0 = 0.f, a1 = 0.f, a2 = 0.f, a3 = 0.f;                         \
        for (; i + 8 <= cnt; i += 8) {                                        \
            int s0 = sp[i],     s1 = sp[i + 1], s2 = sp[i + 2], s3 = sp[i + 3];\
            int s4 = sp[i + 4], s5 = sp[i + 5], s6 = sp[i + 6], s7 = sp[i + 7];\
            float h0 = bf2f(Hh[(size_t)s0 * 64 + (lane)]);                    \
            float h1 = bf2f(Hh[(size_t)s1 * 64 + (lane)]);                    \
            float h2 = bf2f(Hh[(size_t)s2 * 64 + (lane)]);                    \
            float h3 = bf2f(Hh[(size_t)s3 * 64 + (lane)]);                    \
            float h4 = bf2f(Hh[(size_t)s4 * 64 + (lane)]);                    \
            float h5 = bf2f(Hh[(size_t)s5 * 64 + (lane)]);                    \
            float h6 = bf2f(Hh[(size_t)s6 * 64 + (lane)]);                    \
            float h7 = bf2f(Hh[(size_t)s7 * 64 + (lane)]);                    \
            a0 += h0 + h1; a1 += h2 + h3; a2 += h4 + h5; a3 += h6 + h7;       \
        }                                                                     \
        if (i + 4 <= cnt) {                                                   \
            int s0 = sp[i], s1 = sp[i + 1], s2 = sp[i + 2], s3 = sp[i + 3];   \
            float h0 = bf2f(Hh[(size_t)s0 * 64 + (lane)]);                    \
            float h1 = bf2f(Hh[(size_t)s1 * 64 + (lane)]);                    \
            float h2 = bf2f(Hh[(size_t)s2 * 64 + (lane)]);                    \
            float h3 = bf2f(Hh[(size_t)s3 * 64 + (lane)]);                    \
            a0 += h0 + h1; a1 += h2 + h3;                                     \
            i += 4;                                                           \
        }                                                                     \
        for (; i < cnt; ++i) a0 += bf2f(Hh[(size_t)sp[i] * 64 + (lane)]);     \
        acc += (a0 + a1) + (a2 + a3);                                         \
    }

// ---------------------------------------------------------------------------
// aggA: h1 = leaky(dis*agg(Hs1) + b1); Hs2 = (h1 @ W2)*dis -> bf16
// ---------------------------------------------------------------------------
__global__ __launch_bounds__(256) void aggA_kernel(
    const unsigned short* __restrict__ Hh, const int* __restrict__ rp,
    const int* __restrict__ ssrc, const float* __restrict__ dis,
    const float* __restrict__ b1, const float* __restrict__ W2,
    unsigned short* __restrict__ Oh, int n) {
    int lane = threadIdx.x & 63;
    float wc[64];
#pragma unroll
    for (int k = 0; k < 64; ++k) wc[k] = W2[k * 64 + lane];
    float bias = b1[lane];

    int wid = (int)((blockIdx.x * blockDim.x + threadIdx.x) >> 6);
    int nwaves = (int)((gridDim.x * blockDim.x) >> 6);
    for (; wid < n; wid += nwaves) {
        GATHER_BODY(Hh, wid, lane)
        float d = dis[wid];
        float h = fmaf(acc, d, bias);
        h = h > 0.f ? h : LEAKY_SLOPE * h;
        int hb = __builtin_bit_cast(int, h);
        float o = 0.f;
#pragma unroll
        for (int k = 0; k < 64; ++k) {
            float hk = __builtin_bit_cast(float, __builtin_amdgcn_readlane(hb, k));
            o = fmaf(hk, wc[k], o);
        }
        Oh[(size_t)wid * 64 + lane] = f2bf(o * d);
    }
}

// ---------------------------------------------------------------------------
// aggB: h2 = leaky(dis*agg(Hs2) + b2); h2s = h2*dis -> bf16
// ---------------------------------------------------------------------------
__global__ __launch_bounds__(256) void aggB_kernel(
    const unsigned short* __restrict__ Hh, const int* __restrict__ rp,
    const int* __restrict__ ssrc, const float* __restrict__ dis,
    const float* __restrict__ b2, unsigned short* __restrict__ Oh, int n) {
    int lane = threadIdx.x & 63;
    float bias = b2[lane];
    int wid = (int)((blockIdx.x * blockDim.x + threadIdx.x) >> 6);
    int nwaves = (int)((gridDim.x * blockDim.x) >> 6);
    for (; wid < n; wid += nwaves) {
        GATHER_BODY(Hh, wid, lane)
        float d = dis[wid];
        float h = fmaf(acc, d, bias);
        h = h > 0.f ? h : LEAKY_SLOPE * h;
        Oh[(size_t)wid * 64 + lane] = f2bf(h * d);
    }
}

// ---------------------------------------------------------------------------
// aggC: g = dis*agg(h2s); mu = g@Wmu + bmu; ls = g@Wls + bls -> d_out
// lanes 0-31 own mu channels, lanes 32-63 own ls channels.
// ---------------------------------------------------------------------------
__global__ __launch_bounds__(256) void aggC_kernel(
    const unsigned short* __restrict__ Hh, const int* __restrict__ rp,
    const int* __restrict__ ssrc, const float* __restrict__ dis,
    const float* __restrict__ Wmu, const float* __restrict__ bmu,
    const float* __restrict__ Wls, const float* __restrict__ bls,
    float* __restrict__ mu, float* __restrict__ ls, int n) {
    int lane = threadIdx.x & 63;
    int half = lane >> 5;
    int c = lane & 31;
    const float* Wp = half ? Wls : Wmu;
    float wc[64];
#pragma unroll
    for (int k = 0; k < 64; ++k) wc[k] = Wp[k * 32 + c];
    float bias = half ? bls[c] : bmu[c];
    float* outp = half ? ls : mu;

    int wid = (int)((blockIdx.x * blockDim.x + threadIdx.x) >> 6);
    int nwaves = (int)((gridDim.x * blockDim.x) >> 6);
    for (; wid < n; wid += nwaves) {
        GATHER_BODY(Hh, wid, lane)
        float gval = acc * dis[wid];
        int gb = __builtin_bit_cast(int, gval);
        float o = bias;
#pragma unroll
        for (int k = 0; k < 64; ++k) {
            float gk = __builtin_bit_cast(float, __builtin_amdgcn_readlane(gb, k));
            o = fmaf(gk, wc[k], o);
        }
        outp[(size_t)wid * 32 + c] = o;
    }
}

// ---------------------------------------------------------------------------
extern "C" void kernel_launch(void* const* d_in, const int* in_sizes, int n_in,
                              void* d_out, int out_size, void* d_ws, size_t ws_size,
                              hipStream_t stream) {
    const float* x   = (const float*)d_in[0];
    const int*   ei  = (const int*)d_in[1];
    const float* W1  = (const float*)d_in[2];
    const float* b1  = (const float*)d_in[3];
    const float* W2  = (const float*)d_in[4];
    const float* b2  = (const float*)d_in[5];
    const float* Wmu = (const float*)d_in[6];
    const float* bmu = (const float*)d_in[7];
    const float* Wls = (const float*)d_in[8];
    const float* bls = (const float*)d_in[9];

    const int N = in_sizes[0] / 128;   // 100000
    const int E = in_sizes[1] / 2;     // 1600000
    const int* src  = ei;
    const int* dstp = ei + E;

    auto align64 = [](size_t v) { return (v + 63) & ~(size_t)63; };
    char* ws = (char*)d_ws;
    int*   deg  = (int*)ws;   ws += align64((size_t)N * 4);
    int*   rp   = (int*)ws;   ws += align64((size_t)(N + 1) * 4);
    int*   next = (int*)ws;   ws += align64((size_t)N * 4);
    float* dis  = (float*)ws; ws += align64((size_t)N * 4);
    int*   bsum = (int*)ws;   ws += 4096;
    int*   ssrc = (int*)ws;   ws += align64((size_t)E * 4);
    unsigned short* bufH0 = (unsigned short*)ws; ws += align64((size_t)N * 64 * 2);
    unsigned short* bufH1 = (unsigned short*)ws; ws += align64((size_t)N * 64 * 2);

    float* mu = (float*)d_out;
    float* ls = mu + (size_t)N * 32;

    const int eblocks = (E + 255) / 256;   // 6250
    const int nblocks = (N + 255) / 256;   // 391

    // ---- CSR build + normalization ----
    hipMemsetAsync(deg, 0, (size_t)N * sizeof(int), stream);
    count_kernel<<<eblocks, 256, 0, stream>>>(dstp, deg, E);
    scan_block_sums<<<nblocks, 256, 0, stream>>>(deg, bsum, N);
    scan_partials<<<1, 512, 0, stream>>>(bsum, nblocks, rp + N, E);
    scan_final<<<nblocks, 256, 0, stream>>>(deg, bsum, rp, next, dis, N);
    fill_kernel<<<eblocks, 256, 0, stream>>>(src, dstp, next, ssrc, E);

    // ---- Hs1 = (x@W1)*dis (bf16) ----
    gemm1_kernel<<<N / 16, 256, 0, stream>>>(x, W1, dis, bufH0, N);

    const int aggblocks = 2048;  // 8192 waves, grid-stride

    aggA_kernel<<<aggblocks, 256, 0, stream>>>(bufH0, rp, ssrc, dis, b1, W2, bufH1, N);
    aggB_kernel<<<aggblocks, 256, 0, stream>>>(bufH1, rp, ssrc, dis, b2, bufH0, N);
    aggC_kernel<<<aggblocks, 256, 0, stream>>>(bufH0, rp, ssrc, dis, Wmu, bmu,
                                               Wls, bls, mu, ls, N);
}